// Round 7
// baseline (798.682 us; speedup 1.0000x reference)
//
#include <hip/hip_runtime.h>
#include <hip/hip_bf16.h>
#include <stdint.h>

// CNF step: 4-layer tanh MLP (33->1024->1024->1024->32) forward + exact
// Jacobian trace via 32 forward-mode tangents. B=4096, H=1024, D=32.
// f32 in/out; bf16 MFMA internally.
//
// R19: occupancy attack. R18 (t0-fused jvp1, 735us) showed the 2-phase jvp
// core is register-limited: 128 VGPR + 128 AGPR (acc[8][4]) = 256/wave ->
// 2 waves/SIMD (m69 boundary) -> 8 waves/CU -> only one partner block for
// the implicit cross-block overlap that all measured wins rely on (m114).
// R13-R16 changed schedules at FIXED residency and all lost. This round
// halves the accumulator instead: MF=4 (128x128 tile, acc 64 AGPR, ~100
// VGPR ~= 164 total <= 170) -> 3 waves/SIMD, 12 waves/CU, 3 resident
// blocks (+50% overlap capacity). DS/MFMA ratio worsens 0.75->1.0 but
// those pipes overlap across blocks. __launch_bounds__(256,3) on all GEMM
// kernels. jvp1f t0-build adapted: one sample per wave (1 h-load + 4
// W0T-loads + 4 swizzled b128 writes/thread; same verified swizzle
// identity LDS[row][s]=global[row][s^(row&7)]). prep/fwd3 unchanged.

using bf  = __hip_bfloat16;
using bf2 = __hip_bfloat162;
typedef __attribute__((ext_vector_type(8))) short bf16x8;   // 8 bf16 = 4 VGPRs
typedef __attribute__((ext_vector_type(4))) float f32x4;    // C/D frag

__device__ __forceinline__ float b2f(bf x)    { return __bfloat162float(x); }
__device__ __forceinline__ bf    f2b(float x) { return __float2bfloat16(x); }
__device__ __forceinline__ float s2f(short s) {
  return __uint_as_float(((unsigned)(unsigned short)s) << 16);
}

__device__ __forceinline__ void gld16(const void* g, void* l) {
  __builtin_amdgcn_global_load_lds((const __attribute__((address_space(1))) void*)g,
                                   (__attribute__((address_space(3))) void*)l,
                                   16, 0, 0);
}

// ---------------------------------------------------------------- small bodies
__device__ __forceinline__ void conv_body(int blk, const float* __restrict__ src,
                                          bf* __restrict__ dst, int n4) {
  const int i = blk * 256 + threadIdx.x;
  if (i >= n4) return;
  float4 v = ((const float4*)src)[i];
  bf2* d = (bf2*)(dst + (size_t)i * 4);
  d[0] = __float22bfloat162_rn(make_float2(v.x, v.y));
  d[1] = __float22bfloat162_rn(make_float2(v.z, v.w));
}

__device__ __forceinline__ void w0t_body(int blk, const float* __restrict__ W0,
                                         bf* __restrict__ W0T) {
  const int idx = blk * 256 + threadIdx.x;
  const int i = idx >> 10, q = idx & 1023;
  W0T[idx] = f2b(W0[q * 33 + i]);
}

// ---------------------------------------------------------------- prep
// [0,128): fwd0 | [128,1152): conv W1 | [1152,2176): conv W2
// [2176,2208): conv W3 | [2208,2336): W0T | 2336: zero divv region
__global__ __launch_bounds__(256) void prep_k(const float* __restrict__ z,
                                              const float* __restrict__ tin,
                                              const float* __restrict__ W0,
                                              const float* __restrict__ b0,
                                              const float* __restrict__ W1,
                                              const float* __restrict__ W2,
                                              const float* __restrict__ W3,
                                              bf* __restrict__ h0,
                                              bf* __restrict__ W0T,
                                              bf* __restrict__ W1b,
                                              bf* __restrict__ W2b,
                                              bf* __restrict__ W3b,
                                              float* __restrict__ out2) {
  __shared__ float zs[32 * 33];
  const int f = blockIdx.x, t = threadIdx.x;
  if (f < 128) {  // fwd0: 32 samples/block
    const int s0 = f * 32;
    for (int j = t; j < 1024; j += 256) {
      const int s = j >> 5, k = j & 31;
      zs[s * 33 + k] = z[(size_t)(s0 + s) * 32 + k];
    }
    if (t < 32) zs[t * 33 + 32] = tin[0];
    __syncthreads();
#pragma unroll 1
    for (int rep = 0; rep < 4; ++rep) {
      const int hh = rep * 256 + t;
      const float* wr = W0 + (size_t)hh * 33;
      float wv[33];
#pragma unroll
      for (int k = 0; k < 33; ++k) wv[k] = wr[k];
      const float bv = b0[hh];
#pragma unroll 1
      for (int s = 0; s < 32; ++s) {
        float acc = bv;
#pragma unroll
        for (int k = 0; k < 33; ++k) acc += wv[k] * zs[s * 33 + k];
        h0[(size_t)(s0 + s) * 1024 + hh] = f2b(tanhf(acc));
      }
    }
  } else if (f < 1152) {
    conv_body(f - 128, W1, W1b, 262144);
  } else if (f < 2176) {
    conv_body(f - 1152, W2, W2b, 262144);
  } else if (f < 2208) {
    conv_body(f - 2176, W3, W3b, 8192);
  } else if (f < 2336) {
    w0t_body(f - 2208, W0, W0T);
  } else {
#pragma unroll
    for (int u = 0; u < 16; ++u) out2[u * 256 + t] = 0.f;
  }
}

// ---------------------------------------------------------------- GEMM core
// (MF*32)x128 block tile, (MF*16)x64 wave-tile (MFx4 frags), BK=64,
// glds(16B) staging with global-side XOR swizzle -> conflict-free reads,
// no ds_write instructions. MF=4: 128x128 tile (fwd + jvp2).
template <int MF>
__device__ __forceinline__ void gemm_core(bf* As, bf* Bs,
                                          const bf* __restrict__ A,
                                          const bf* __restrict__ B,
                                          size_t m0, size_t n0,
                                          f32x4 (&acc)[MF][4]) {
  constexpr int K = 1024;
  const int t = threadIdx.x, l = t & 63, w = t >> 6;
  const int wm = w >> 1, wn = w & 1;
  const int r15 = l & 15, q4 = l >> 4, sw = r15 & 7;

  // staging geometry: lane l covers row sub-index l>>3, seg (l&7)^(l>>3)
  const int lrow = l >> 3;
  const int lseg = (l & 7) ^ lrow;
  const bf* asrc[MF]; bf* alds[MF];
  const bf* bsrc[4]; bf* blds[4];
#pragma unroll
  for (int u = 0; u < MF; ++u) {
    const int row = w * (MF * 8) + u * 8 + lrow;     // A rows [w*MF*8, +MF*8)
    asrc[u] = A + (m0 + row) * K + lseg * 8;
    alds[u] = As + (size_t)(w * (MF * 8) + u * 8) * 64;  // wave-uniform base
  }
#pragma unroll
  for (int u = 0; u < 4; ++u) {
    const int row = w * 32 + u * 8 + lrow;           // B rows [w*32, w*32+32)
    bsrc[u] = B + (n0 + row) * K + lseg * 8;
    blds[u] = Bs + (size_t)(w * 32 + u * 8) * 64;
  }

#pragma unroll 1
  for (int k0 = 0; k0 < K; k0 += 64) {
#pragma unroll
    for (int u = 0; u < MF; ++u) gld16(asrc[u] + k0, alds[u]);
#pragma unroll
    for (int u = 0; u < 4; ++u) gld16(bsrc[u] + k0, blds[u]);
    __syncthreads();
#pragma unroll
    for (int kk = 0; kk < 2; ++kk) {
      const int sa = (kk * 4 + q4) ^ sw;
      bf16x8 af[MF], bfr[4];
#pragma unroll
      for (int i = 0; i < MF; ++i)
        af[i] = *(const bf16x8*)(As + (wm * (MF * 16) + i * 16 + r15) * 64 + sa * 8);
#pragma unroll
      for (int j = 0; j < 4; ++j)
        bfr[j] = *(const bf16x8*)(Bs + (wn * 64 + j * 16 + r15) * 64 + sa * 8);
#pragma unroll
      for (int mi = 0; mi < MF; ++mi)
#pragma unroll
        for (int ni = 0; ni < 4; ++ni)
          acc[mi][ni] = __builtin_amdgcn_mfma_f32_16x16x32_bf16(af[mi], bfr[ni], acc[mi][ni], 0, 0, 0);
    }
    __syncthreads();
  }
}

// ---------------------------------------------------------------- fwd GEMM
// MF=4: 128x128 tile, 256 blocks (32 m x 8 n) -> full GPU.
__global__ __launch_bounds__(256, 3) void gemm_fwd(const bf* __restrict__ A,
                                                   const bf* __restrict__ W,
                                                   const float* __restrict__ bias,
                                                   bf* __restrict__ H) {
  constexpr int N = 1024;
  __shared__ __align__(16) bf As[128 * 64];
  __shared__ __align__(16) bf Bs[128 * 64];
  const int t = threadIdx.x, l = t & 63, w = t >> 6;
  const int wm = w >> 1, wn = w & 1;
  const int f = blockIdx.x;                   // 256 blocks: 32 m x 8 n
  const int n_t = (f >> 3) & 7, m_t = (f & 7) + 8 * (f >> 6);
  const size_t m0 = (size_t)m_t * 128, n0 = (size_t)n_t * 128;
  const int r15 = l & 15, q4 = l >> 4;
  f32x4 acc[4][4] = {};
  gemm_core<4>(As, Bs, A, W, m0, n0, acc);
#pragma unroll
  for (int ni = 0; ni < 4; ++ni) {
    const int n = (int)n0 + wn * 64 + ni * 16 + r15;
    const float bv = bias[n];
#pragma unroll
    for (int mi = 0; mi < 4; ++mi)
#pragma unroll
      for (int r = 0; r < 4; ++r) {
        const size_t m = m0 + wm * 64 + mi * 16 + q4 * 4 + r;
        H[m * N + n] = f2b(tanhf(acc[mi][ni][r] + bv));
      }
  }
}

// ---------------------------------------------------------------- fwd3 (out)
__global__ __launch_bounds__(256) void fwd3_k(const bf* __restrict__ h2,
                                              const bf* __restrict__ W3b,
                                              const float* __restrict__ b3,
                                              float* __restrict__ out) {
  __shared__ __align__(16) bf hs[8 * 1024];
  const int t = threadIdx.x;
  const size_t bb = (size_t)blockIdx.x * 8;
  const uint4* src = (const uint4*)(h2 + bb * 1024);
  uint4* dv = (uint4*)hs;
#pragma unroll
  for (int j = 0; j < 4; ++j) dv[j * 256 + t] = src[j * 256 + t];
  __syncthreads();
  const int i = t & 31, bl = t >> 5;
  const bf2* hr = (const bf2*)(hs + bl * 1024);
  const bf2* wr = (const bf2*)(W3b + (size_t)i * 1024);
  float s = 0.f;
#pragma unroll 8
  for (int k2 = 0; k2 < 512; ++k2) {
    float2 a = __bfloat1622float2(hr[k2]);
    float2 c = __bfloat1622float2(wr[k2]);
    s += a.x * c.x + a.y * c.y;
  }
  out[(bb + bl) * 32 + i] = s + b3[i];
}

// ---------------------------------------------------------------- jvp1 (fused t0, MF=4)
// 128x128 tile; A-tile built in LDS: T0[(b,i),k] = (1-h0[b,k]^2)*W0T[i,k].
// Wave w owns sample b0+w (rows w*32..w*32+32 = tangents u*8+lrow).
// Thread: 1 h-load + 4 W0T-loads (16B, L1/L2-hot) + 4 swizzled b128 writes;
// LDS[row][s] = global[row][s^(row&7)] (verified identity, 2-way write
// aliasing = free). Next-iter inputs prefetched before the barrier.
__global__ __launch_bounds__(256, 3) void gemm_jvp1f(const bf* __restrict__ h0c,
                                                     const bf* __restrict__ W0T,
                                                     const bf* __restrict__ W1b,
                                                     const bf* __restrict__ h1c,
                                                     bf* __restrict__ T1) {
  constexpr int K = 1024;
  __shared__ __align__(16) bf As[128 * 64];
  __shared__ __align__(16) bf Bs[128 * 64];
  const int t = threadIdx.x, l = t & 63, w = t >> 6;
  const int wm = w >> 1, wn = w & 1;
  const int f = blockIdx.x;                 // grid 2NB: NB/4 m_t x 8 n_t
  const int n_t = (f >> 3) & 7, m_t = (f & 7) + 8 * (f >> 6);
  const size_t m0 = (size_t)m_t * 128, n0 = (size_t)n_t * 128;
  const int r15 = l & 15, q4 = l >> 4, sw = r15 & 7;
  const int lrow = l >> 3, kseg = l & 7;
  const int lseg = kseg ^ lrow;

  // B staging (gld16 path, identical to gemm_core<4> B side)
  const bf* bsrc[4]; bf* blds[4];
#pragma unroll
  for (int u = 0; u < 4; ++u) {
    const int row = w * 32 + u * 8 + lrow;
    bsrc[u] = W1b + (n0 + row) * K + lseg * 8;
    blds[u] = Bs + (size_t)(w * 32 + u * 8) * 64;
  }

  // A build sources: wave w -> sample b0+w; W0T rows u*8+lrow
  const int b0 = (int)(m0 >> 5);
  const bf* hp = h0c + (size_t)(b0 + w) * K + kseg * 8;
  const bf* wp[4];
#pragma unroll
  for (int u = 0; u < 4; ++u) wp[u] = W0T + (size_t)(u * 8 + lrow) * K + kseg * 8;
  bf* awr[4];
#pragma unroll
  for (int u = 0; u < 4; ++u)
    awr[u] = As + (size_t)(w * 32 + u * 8 + lrow) * 64 + lseg * 8;

  f32x4 acc[4][4] = {};
  // preload k-phase 0 inputs
  bf16x8 hv = *(const bf16x8*)hp;
  bf16x8 wv[4];
#pragma unroll
  for (int u = 0; u < 4; ++u) wv[u] = *(const bf16x8*)wp[u];

#pragma unroll 1
  for (int k0 = 0; k0 < K; k0 += 64) {
#pragma unroll
    for (int u = 0; u < 4; ++u) gld16(bsrc[u] + k0, blds[u]);
    // a = 1-h^2 (f32), then 4 swizzled b128 row writes
    float a[8];
#pragma unroll
    for (int e = 0; e < 8; ++e) {
      const float h = s2f(hv[e]);
      a[e] = 1.f - h * h;
    }
#pragma unroll
    for (int u = 0; u < 4; ++u) {
      const bf16x8 wvu = wv[u];
      union { bf2 b[4]; uint4 u4; } o;
#pragma unroll
      for (int p = 0; p < 4; ++p)
        o.b[p] = __float22bfloat162_rn(make_float2(a[2 * p] * s2f(wvu[2 * p]),
                                                   a[2 * p + 1] * s2f(wvu[2 * p + 1])));
      *(uint4*)awr[u] = o.u4;
    }
    // prefetch next k-phase inputs (wraps on last iter; data unused)
    const int kn = (k0 + 64) & (K - 1);
    hv = *(const bf16x8*)(hp + kn);
#pragma unroll
    for (int u = 0; u < 4; ++u) wv[u] = *(const bf16x8*)(wp[u] + kn);
    __syncthreads();
#pragma unroll
    for (int kk = 0; kk < 2; ++kk) {
      const int sa = (kk * 4 + q4) ^ sw;
      bf16x8 af[4], bfr[4];
#pragma unroll
      for (int i = 0; i < 4; ++i)
        af[i] = *(const bf16x8*)(As + (wm * 64 + i * 16 + r15) * 64 + sa * 8);
#pragma unroll
      for (int j = 0; j < 4; ++j)
        bfr[j] = *(const bf16x8*)(Bs + (wn * 64 + j * 16 + r15) * 64 + sa * 8);
#pragma unroll
      for (int mi = 0; mi < 4; ++mi)
#pragma unroll
        for (int ni = 0; ni < 4; ++ni)
          acc[mi][ni] = __builtin_amdgcn_mfma_f32_16x16x32_bf16(af[mi], bfr[ni], acc[mi][ni], 0, 0, 0);
    }
    __syncthreads();
  }

  const int bbase = (int)((m0 + wm * 64) >> 5);  // 2 samples per wave
#pragma unroll
  for (int ni = 0; ni < 4; ++ni) {
    const int n = (int)n0 + wn * 64 + ni * 16 + r15;
    float a1v[2];
#pragma unroll
    for (int s = 0; s < 2; ++s) {
      const float hv1 = b2f(h1c[(size_t)(bbase + s) * 1024 + n]);
      a1v[s] = 1.f - hv1 * hv1;
    }
#pragma unroll
    for (int mi = 0; mi < 4; ++mi)
#pragma unroll
      for (int r = 0; r < 4; ++r) {
        const size_t m = m0 + wm * 64 + mi * 16 + q4 * 4 + r;
        T1[m * 1024 + n] = f2b(a1v[mi >> 1] * acc[mi][ni][r]);
      }
  }
}

// ---------------------------------------------------------------- jvp2 (MF=4)
__global__ __launch_bounds__(256, 3) void gemm_jvp2(const bf* __restrict__ T1,
                                                    const bf* __restrict__ W2b,
                                                    const bf* __restrict__ W3b,
                                                    const bf* __restrict__ h2c,
                                                    float* __restrict__ out2c) {
  __shared__ __align__(16) bf As[128 * 64];
  __shared__ __align__(16) bf Bs[128 * 64];
  const int t = threadIdx.x, l = t & 63, w = t >> 6;
  const int wm = w >> 1, wn = w & 1;
  const int f = blockIdx.x;                 // grid 2NB
  const int n_t = (f >> 3) & 7, m_t = (f & 7) + 8 * (f >> 6);
  const size_t m0 = (size_t)m_t * 128, n0 = (size_t)n_t * 128;
  const int r15 = l & 15, q4 = l >> 4;
  f32x4 acc[4][4] = {};
  gemm_core<4>(As, Bs, T1, W2b, m0, n0, acc);
  const int bbase = (int)((m0 + wm * 64) >> 5);  // 2 samples per wave
  float part[2] = {0.f, 0.f};
#pragma unroll
  for (int ni = 0; ni < 4; ++ni) {
    const int n = (int)n0 + wn * 64 + ni * 16 + r15;  // = p
    float a2v[2];
#pragma unroll
    for (int s = 0; s < 2; ++s) {
      const float hv = b2f(h2c[(size_t)(bbase + s) * 1024 + n]);
      a2v[s] = 1.f - hv * hv;
    }
#pragma unroll
    for (int mi = 0; mi < 4; ++mi) {
      const int isel = mi >> 1;
#pragma unroll
      for (int r = 0; r < 4; ++r) {
        const int mm = wm * 64 + mi * 16 + q4 * 4 + r;  // i = mm & 31
        part[isel] += b2f(W3b[(size_t)(mm & 31) * 1024 + n]) * a2v[isel] * acc[mi][ni][r];
      }
    }
  }
#pragma unroll
  for (int off = 32; off > 0; off >>= 1) {
#pragma unroll
    for (int s = 0; s < 2; ++s) part[s] += __shfl_down(part[s], off);
  }
  if (l == 0) {
#pragma unroll
    for (int s = 0; s < 2; ++s) atomicAdd(out2c + bbase + s, -part[s]);
  }
}

// ================================================================ launch
extern "C" void kernel_launch(void* const* d_in, const int* in_sizes, int n_in,
                              void* d_out, int out_size, void* d_ws, size_t ws_size,
                              hipStream_t stream) {
  const float* tin = (const float*)d_in[0];
  const float* z   = (const float*)d_in[1];
  const float* W0  = (const float*)d_in[2];
  const float* b0  = (const float*)d_in[3];
  const float* W1  = (const float*)d_in[4];
  const float* b1  = (const float*)d_in[5];
  const float* W2  = (const float*)d_in[6];
  const float* b2  = (const float*)d_in[7];
  const float* W3  = (const float*)d_in[8];
  const float* b3  = (const float*)d_in[9];
  float* out = (float*)d_out;
  float* out2 = out + 131072;  // divv region, zeroed by prep
  (void)in_sizes; (void)n_in; (void)out_size;

  char* ws = (char*)d_ws;
  size_t off = 0;
  auto take = [&](size_t bytes) {
    char* p = ws + off;
    off = (off + bytes + 255) & ~(size_t)255;
    return p;
  };
  bf* h0   = (bf*)take((size_t)4096 * 1024 * 2);   // 8 MB
  bf* h1   = (bf*)take((size_t)4096 * 1024 * 2);   // 8 MB
  bf* h2   = (bf*)take((size_t)4096 * 1024 * 2);   // 8 MB
  bf* W0T  = (bf*)take((size_t)32 * 1024 * 2);     // 64 KB
  bf* W1b  = (bf*)take((size_t)1024 * 1024 * 2);   // 2 MB
  bf* W2b  = (bf*)take((size_t)1024 * 1024 * 2);   // 2 MB
  bf* W3b  = (bf*)take((size_t)32 * 1024 * 2);     // 64 KB
  const size_t avail = (ws_size > off) ? (ws_size - off) : 0;
  int NB = 4096;
  while (NB > 256 && (size_t)NB * 65536 > avail) NB >>= 1;  // only T1
  bf* T1 = (bf*)take((size_t)NB * 65536);

  prep_k<<<dim3(2337), dim3(256), 0, stream>>>(z, tin, W0, b0, W1, W2, W3,
                                               h0, W0T, W1b, W2b, W3b, out2);
  gemm_fwd<<<dim3(256), dim3(256), 0, stream>>>(h0, W1b, b1, h1);
  gemm_fwd<<<dim3(256), dim3(256), 0, stream>>>(h1, W2b, b2, h2);
  fwd3_k<<<dim3(512), dim3(256), 0, stream>>>(h2, W3b, b3, out);
  for (int cb = 0; cb < 4096; cb += NB) {
    gemm_jvp1f<<<dim3(2 * NB), dim3(256), 0, stream>>>(
        h0 + (size_t)cb * 1024, W0T, W1b, h1 + (size_t)cb * 1024, T1);
    gemm_jvp2<<<dim3(2 * NB), dim3(256), 0, stream>>>(
        T1, W2b, W3b, h2 + (size_t)cb * 1024, out2 + cb);
  }
}

// Round 9
// 753.866 us; speedup vs baseline: 1.0594x; 1.0594x over previous
//
#include <hip/hip_runtime.h>
#include <hip/hip_bf16.h>
#include <stdint.h>

// CNF step: 4-layer tanh MLP (33->1024->1024->1024->32) forward + exact
// Jacobian trace via 32 forward-mode tangents. B=4096, H=1024, D=32.
// f32 in/out; bf16 MFMA internally.
//
// R21 = R20 resubmitted verbatim (previous round's bench was an
// infrastructure failure: "MI355X container failed twice"; no evidence
// against the kernel).
//
// R20: revert to R18 (735us, best) + W3-transpose epilogue in jvp2.
// R19 (MF=4, 3 blocks/CU) refuted: +33% LDS-read per FLOP at MF=4 and the
// jvp core is LDS-READ-BANDWIDTH-BOUND: per CU-slot DS ~= 192 b128 x 8cy =
// 1536cy vs MFMA wall 620cy vs measured slot ~1630cy -> DS ~94% busy,
// MfmaUtil 38%. All structural results fit this model (R15 conflicts 1:1,
// R16 TA scatter, R19 DS/FLOP). 128x64 wave-tile is reg-file-maximal for
// 2 waves/SIMD -> DS/FLOP floor for bf16. Safe fix this round: jvp2's
// epilogue read W3b by ROW-scatter (32 scalar loads/lane, ~512 line
// touches/wave); prep now emits W3T[n][i] so each lane reads its i-range
// as 2x8B vectors per ni (8 loads/lane, 4x fewer line touches). Same f32
// ->bf16 values -> bit-identical output. Everything else = R18 verbatim.

using bf  = __hip_bfloat16;
using bf2 = __hip_bfloat162;
typedef __attribute__((ext_vector_type(8))) short bf16x8;   // 8 bf16 = 4 VGPRs
typedef __attribute__((ext_vector_type(4))) short bf16x4;   // 4 bf16 = 8 B
typedef __attribute__((ext_vector_type(4))) float f32x4;    // C/D frag

__device__ __forceinline__ float b2f(bf x)    { return __bfloat162float(x); }
__device__ __forceinline__ bf    f2b(float x) { return __float2bfloat16(x); }
__device__ __forceinline__ float s2f(short s) {
  return __uint_as_float(((unsigned)(unsigned short)s) << 16);
}

__device__ __forceinline__ void gld16(const void* g, void* l) {
  __builtin_amdgcn_global_load_lds((const __attribute__((address_space(1))) void*)g,
                                   (__attribute__((address_space(3))) void*)l,
                                   16, 0, 0);
}

// ---------------------------------------------------------------- small bodies
__device__ __forceinline__ void conv_body(int blk, const float* __restrict__ src,
                                          bf* __restrict__ dst, int n4) {
  const int i = blk * 256 + threadIdx.x;
  if (i >= n4) return;
  float4 v = ((const float4*)src)[i];
  bf2* d = (bf2*)(dst + (size_t)i * 4);
  d[0] = __float22bfloat162_rn(make_float2(v.x, v.y));
  d[1] = __float22bfloat162_rn(make_float2(v.z, v.w));
}

__device__ __forceinline__ void w0t_body(int blk, const float* __restrict__ W0,
                                         bf* __restrict__ W0T) {
  const int idx = blk * 256 + threadIdx.x;
  const int i = idx >> 10, q = idx & 1023;
  W0T[idx] = f2b(W0[q * 33 + i]);
}

__device__ __forceinline__ void w3t_body(int blk, const float* __restrict__ W3,
                                         bf* __restrict__ W3T) {
  const int idx = blk * 256 + threadIdx.x;   // [0, 32768)
  const int n = idx >> 5, i = idx & 31;
  W3T[idx] = f2b(W3[(size_t)i * 1024 + n]);
}

// ---------------------------------------------------------------- prep
// [0,128): fwd0 | [128,1152): conv W1 | [1152,2176): conv W2
// [2176,2208): conv W3 | [2208,2336): W0T | [2336,2464): W3T | 2464: zero
__global__ __launch_bounds__(256) void prep_k(const float* __restrict__ z,
                                              const float* __restrict__ tin,
                                              const float* __restrict__ W0,
                                              const float* __restrict__ b0,
                                              const float* __restrict__ W1,
                                              const float* __restrict__ W2,
                                              const float* __restrict__ W3,
                                              bf* __restrict__ h0,
                                              bf* __restrict__ W0T,
                                              bf* __restrict__ W1b,
                                              bf* __restrict__ W2b,
                                              bf* __restrict__ W3b,
                                              bf* __restrict__ W3T,
                                              float* __restrict__ out2) {
  __shared__ float zs[32 * 33];
  const int f = blockIdx.x, t = threadIdx.x;
  if (f < 128) {  // fwd0: 32 samples/block
    const int s0 = f * 32;
    for (int j = t; j < 1024; j += 256) {
      const int s = j >> 5, k = j & 31;
      zs[s * 33 + k] = z[(size_t)(s0 + s) * 32 + k];
    }
    if (t < 32) zs[t * 33 + 32] = tin[0];
    __syncthreads();
#pragma unroll 1
    for (int rep = 0; rep < 4; ++rep) {
      const int hh = rep * 256 + t;
      const float* wr = W0 + (size_t)hh * 33;
      float wv[33];
#pragma unroll
      for (int k = 0; k < 33; ++k) wv[k] = wr[k];
      const float bv = b0[hh];
#pragma unroll 1
      for (int s = 0; s < 32; ++s) {
        float acc = bv;
#pragma unroll
        for (int k = 0; k < 33; ++k) acc += wv[k] * zs[s * 33 + k];
        h0[(size_t)(s0 + s) * 1024 + hh] = f2b(tanhf(acc));
      }
    }
  } else if (f < 1152) {
    conv_body(f - 128, W1, W1b, 262144);
  } else if (f < 2176) {
    conv_body(f - 1152, W2, W2b, 262144);
  } else if (f < 2208) {
    conv_body(f - 2176, W3, W3b, 8192);
  } else if (f < 2336) {
    w0t_body(f - 2208, W0, W0T);
  } else if (f < 2464) {
    w3t_body(f - 2336, W3, W3T);
  } else {
#pragma unroll
    for (int u = 0; u < 16; ++u) out2[u * 256 + t] = 0.f;
  }
}

// ---------------------------------------------------------------- GEMM core
// (MF*32)x128 block tile, (MF*16)x64 wave-tile (MFx4 frags), BK=64,
// glds(16B) staging with global-side XOR swizzle -> conflict-free reads,
// no ds_write instructions. MF=8: jvp2. MF=4: 128x128 tile for fwd GEMMs.
template <int MF>
__device__ __forceinline__ void gemm_core(bf* As, bf* Bs,
                                          const bf* __restrict__ A,
                                          const bf* __restrict__ B,
                                          size_t m0, size_t n0,
                                          f32x4 (&acc)[MF][4]) {
  constexpr int K = 1024;
  const int t = threadIdx.x, l = t & 63, w = t >> 6;
  const int wm = w >> 1, wn = w & 1;
  const int r15 = l & 15, q4 = l >> 4, sw = r15 & 7;

  // staging geometry: lane l covers row sub-index l>>3, seg (l&7)^(l>>3)
  const int lrow = l >> 3;
  const int lseg = (l & 7) ^ lrow;
  const bf* asrc[MF]; bf* alds[MF];
  const bf* bsrc[4]; bf* blds[4];
#pragma unroll
  for (int u = 0; u < MF; ++u) {
    const int row = w * (MF * 8) + u * 8 + lrow;     // A rows [w*MF*8, +MF*8)
    asrc[u] = A + (m0 + row) * K + lseg * 8;
    alds[u] = As + (size_t)(w * (MF * 8) + u * 8) * 64;  // wave-uniform base
  }
#pragma unroll
  for (int u = 0; u < 4; ++u) {
    const int row = w * 32 + u * 8 + lrow;           // B rows [w*32, w*32+32)
    bsrc[u] = B + (n0 + row) * K + lseg * 8;
    blds[u] = Bs + (size_t)(w * 32 + u * 8) * 64;
  }

#pragma unroll 1
  for (int k0 = 0; k0 < K; k0 += 64) {
#pragma unroll
    for (int u = 0; u < MF; ++u) gld16(asrc[u] + k0, alds[u]);
#pragma unroll
    for (int u = 0; u < 4; ++u) gld16(bsrc[u] + k0, blds[u]);
    __syncthreads();
#pragma unroll
    for (int kk = 0; kk < 2; ++kk) {
      const int sa = (kk * 4 + q4) ^ sw;
      bf16x8 af[MF], bfr[4];
#pragma unroll
      for (int i = 0; i < MF; ++i)
        af[i] = *(const bf16x8*)(As + (wm * (MF * 16) + i * 16 + r15) * 64 + sa * 8);
#pragma unroll
      for (int j = 0; j < 4; ++j)
        bfr[j] = *(const bf16x8*)(Bs + (wn * 64 + j * 16 + r15) * 64 + sa * 8);
#pragma unroll
      for (int mi = 0; mi < MF; ++mi)
#pragma unroll
        for (int ni = 0; ni < 4; ++ni)
          acc[mi][ni] = __builtin_amdgcn_mfma_f32_16x16x32_bf16(af[mi], bfr[ni], acc[mi][ni], 0, 0, 0);
    }
    __syncthreads();
  }
}

// ---------------------------------------------------------------- fwd GEMM
// MF=4: 128x128 tile, 256 blocks (32 m x 8 n) -> full GPU.
__global__ __launch_bounds__(256, 2) void gemm_fwd(const bf* __restrict__ A,
                                                   const bf* __restrict__ W,
                                                   const float* __restrict__ bias,
                                                   bf* __restrict__ H) {
  constexpr int N = 1024;
  __shared__ __align__(16) bf As[128 * 64];
  __shared__ __align__(16) bf Bs[128 * 64];
  const int t = threadIdx.x, l = t & 63, w = t >> 6;
  const int wm = w >> 1, wn = w & 1;
  const int f = blockIdx.x;                   // 256 blocks: 32 m x 8 n
  const int n_t = (f >> 3) & 7, m_t = (f & 7) + 8 * (f >> 6);
  const size_t m0 = (size_t)m_t * 128, n0 = (size_t)n_t * 128;
  const int r15 = l & 15, q4 = l >> 4;
  f32x4 acc[4][4] = {};
  gemm_core<4>(As, Bs, A, W, m0, n0, acc);
#pragma unroll
  for (int ni = 0; ni < 4; ++ni) {
    const int n = (int)n0 + wn * 64 + ni * 16 + r15;
    const float bv = bias[n];
#pragma unroll
    for (int mi = 0; mi < 4; ++mi)
#pragma unroll
      for (int r = 0; r < 4; ++r) {
        const size_t m = m0 + wm * 64 + mi * 16 + q4 * 4 + r;
        H[m * N + n] = f2b(tanhf(acc[mi][ni][r] + bv));
      }
  }
}

// ---------------------------------------------------------------- fwd3 (out)
__global__ __launch_bounds__(256) void fwd3_k(const bf* __restrict__ h2,
                                              const bf* __restrict__ W3b,
                                              const float* __restrict__ b3,
                                              float* __restrict__ out) {
  __shared__ __align__(16) bf hs[8 * 1024];
  const int t = threadIdx.x;
  const size_t bb = (size_t)blockIdx.x * 8;
  const uint4* src = (const uint4*)(h2 + bb * 1024);
  uint4* dv = (uint4*)hs;
#pragma unroll
  for (int j = 0; j < 4; ++j) dv[j * 256 + t] = src[j * 256 + t];
  __syncthreads();
  const int i = t & 31, bl = t >> 5;
  const bf2* hr = (const bf2*)(hs + bl * 1024);
  const bf2* wr = (const bf2*)(W3b + (size_t)i * 1024);
  float s = 0.f;
#pragma unroll 8
  for (int k2 = 0; k2 < 512; ++k2) {
    float2 a = __bfloat1622float2(hr[k2]);
    float2 c = __bfloat1622float2(wr[k2]);
    s += a.x * c.x + a.y * c.y;
  }
  out[(bb + bl) * 32 + i] = s + b3[i];
}

// ---------------------------------------------------------------- jvp1 (fused t0)
// A-tile computed in-kernel: T0[(b,i),k] = (1-h0[b,k]^2)*W0T[i,k].
// Thread (l,w): its LDS seg lseg=(l&7)^lrow for rows (row&7)==lrow holds
// global k-seg (l&7) -> loads are thread-invariant in k-phase. 8 swizzled
// ds_write_b128 cover each 1KB row-group exactly once (conflict-free).
__global__ __launch_bounds__(256, 2) void gemm_jvp1f(const bf* __restrict__ h0c,
                                                     const bf* __restrict__ W0T,
                                                     const bf* __restrict__ W1b,
                                                     const bf* __restrict__ h1c,
                                                     bf* __restrict__ T1) {
  constexpr int K = 1024;
  __shared__ __align__(16) bf As[256 * 64];
  __shared__ __align__(16) bf Bs[128 * 64];
  const int t = threadIdx.x, l = t & 63, w = t >> 6;
  const int wm = w >> 1, wn = w & 1;
  const int f = blockIdx.x;
  const int n_t = (f >> 3) & 7, m_t = (f & 7) + 8 * (f >> 6);
  const size_t m0 = (size_t)m_t * 256, n0 = (size_t)n_t * 128;
  const int r15 = l & 15, q4 = l >> 4, sw = r15 & 7;
  const int lrow = l >> 3, kseg = l & 7;
  const int lseg = kseg ^ lrow;

  // B staging (unchanged gld16 path)
  const bf* bsrc[4]; bf* blds[4];
#pragma unroll
  for (int u = 0; u < 4; ++u) {
    const int row = w * 32 + u * 8 + lrow;
    bsrc[u] = W1b + (n0 + row) * K + lseg * 8;
    blds[u] = Bs + (size_t)(w * 32 + u * 8) * 64;
  }

  // A compute sources: samples b0+2w, b0+2w+1; W0T rows lrow+8j
  const int b0 = (int)(m0 >> 5);
  const bf* hp0 = h0c + (size_t)(b0 + 2 * w) * K + kseg * 8;
  const bf* hp1 = hp0 + K;
  const bf* wp[4];
#pragma unroll
  for (int j = 0; j < 4; ++j) wp[j] = W0T + (size_t)(lrow + 8 * j) * K + kseg * 8;
  bf* awr[8];
#pragma unroll
  for (int u = 0; u < 8; ++u)
    awr[u] = As + (size_t)(w * 64 + u * 8 + lrow) * 64 + lseg * 8;

  f32x4 acc[8][4] = {};
  // preload k-phase 0 inputs
  bf16x8 hv0 = *(const bf16x8*)hp0;
  bf16x8 hv1 = *(const bf16x8*)hp1;
  bf16x8 wv[4];
#pragma unroll
  for (int j = 0; j < 4; ++j) wv[j] = *(const bf16x8*)wp[j];

#pragma unroll 1
  for (int k0 = 0; k0 < K; k0 += 64) {
#pragma unroll
    for (int u = 0; u < 4; ++u) gld16(bsrc[u] + k0, blds[u]);
    // compute a = 1-h^2 (f32), then write 8 swizzled b128 rows
    float a[2][8];
#pragma unroll
    for (int e = 0; e < 8; ++e) {
      const float h0v = s2f(hv0[e]);
      const float h1v = s2f(hv1[e]);
      a[0][e] = 1.f - h0v * h0v;
      a[1][e] = 1.f - h1v * h1v;
    }
#pragma unroll
    for (int u = 0; u < 8; ++u) {
      const bf16x8 wvu = wv[u & 3];
      const float* aa = a[u >> 2];
      union { bf2 b[4]; uint4 u4; } o;
#pragma unroll
      for (int p = 0; p < 4; ++p)
        o.b[p] = __float22bfloat162_rn(make_float2(aa[2 * p] * s2f(wvu[2 * p]),
                                                   aa[2 * p + 1] * s2f(wvu[2 * p + 1])));
      *(uint4*)awr[u] = o.u4;
    }
    // prefetch next k-phase inputs (wraps on last iter; data unused)
    const int kn = (k0 + 64) & (K - 1);
    hv0 = *(const bf16x8*)(hp0 + kn);
    hv1 = *(const bf16x8*)(hp1 + kn);
#pragma unroll
    for (int j = 0; j < 4; ++j) wv[j] = *(const bf16x8*)(wp[j] + kn);
    __syncthreads();
#pragma unroll
    for (int kk = 0; kk < 2; ++kk) {
      const int sa = (kk * 4 + q4) ^ sw;
      bf16x8 af[8], bfr[4];
#pragma unroll
      for (int i = 0; i < 8; ++i)
        af[i] = *(const bf16x8*)(As + (wm * 128 + i * 16 + r15) * 64 + sa * 8);
#pragma unroll
      for (int j = 0; j < 4; ++j)
        bfr[j] = *(const bf16x8*)(Bs + (wn * 64 + j * 16 + r15) * 64 + sa * 8);
#pragma unroll
      for (int mi = 0; mi < 8; ++mi)
#pragma unroll
        for (int ni = 0; ni < 4; ++ni)
          acc[mi][ni] = __builtin_amdgcn_mfma_f32_16x16x32_bf16(af[mi], bfr[ni], acc[mi][ni], 0, 0, 0);
    }
    __syncthreads();
  }

  const int bbase = (int)((m0 + wm * 128) >> 5);  // 4 samples per wave
#pragma unroll
  for (int ni = 0; ni < 4; ++ni) {
    const int n = (int)n0 + wn * 64 + ni * 16 + r15;
    float a1v[4];
#pragma unroll
    for (int s = 0; s < 4; ++s) {
      const float hv = b2f(h1c[(size_t)(bbase + s) * 1024 + n]);
      a1v[s] = 1.f - hv * hv;
    }
#pragma unroll
    for (int mi = 0; mi < 8; ++mi)
#pragma unroll
      for (int r = 0; r < 4; ++r) {
        const size_t m = m0 + wm * 128 + mi * 16 + q4 * 4 + r;
        T1[m * 1024 + n] = f2b(a1v[mi >> 1] * acc[mi][ni][r]);
      }
  }
}

// ---------------------------------------------------------------- jvp2
// Epilogue uses W3T[n][i]: lane (q4,r15) needs i = (mi&1)*16 + q4*4 + r
// -> 2x bf16x4 loads per ni (vs 32 scalar row-scatters in R18).
__global__ __launch_bounds__(256, 2) void gemm_jvp2(const bf* __restrict__ T1,
                                                    const bf* __restrict__ W2b,
                                                    const bf* __restrict__ W3T,
                                                    const bf* __restrict__ h2c,
                                                    float* __restrict__ out2c) {
  __shared__ __align__(16) bf As[256 * 64];
  __shared__ __align__(16) bf Bs[128 * 64];
  const int t = threadIdx.x, l = t & 63, w = t >> 6;
  const int wm = w >> 1, wn = w & 1;
  const int f = blockIdx.x;
  const int n_t = (f >> 3) & 7, m_t = (f & 7) + 8 * (f >> 6);
  const size_t m0 = (size_t)m_t * 256, n0 = (size_t)n_t * 128;
  const int r15 = l & 15, q4 = l >> 4;
  f32x4 acc[8][4] = {};
  gemm_core<8>(As, Bs, T1, W2b, m0, n0, acc);
  const int bbase = (int)((m0 + wm * 128) >> 5);  // 4 samples per wave
  float part[4] = {0.f, 0.f, 0.f, 0.f};
#pragma unroll
  for (int ni = 0; ni < 4; ++ni) {
    const int n = (int)n0 + wn * 64 + ni * 16 + r15;  // = p
    float a2v[4];
#pragma unroll
    for (int s = 0; s < 4; ++s) {
      const float hv = b2f(h2c[(size_t)(bbase + s) * 1024 + n]);
      a2v[s] = 1.f - hv * hv;
    }
    // W3T row n: this lane needs i in {q4*4+r, 16+q4*4+r}
    const bf16x4 w3lo = *(const bf16x4*)(W3T + (size_t)n * 32 + q4 * 4);
    const bf16x4 w3hi = *(const bf16x4*)(W3T + (size_t)n * 32 + 16 + q4 * 4);
#pragma unroll
    for (int mi = 0; mi < 8; ++mi) {
      const int isel = mi >> 1;
#pragma unroll
      for (int r = 0; r < 4; ++r) {
        const float w3v = s2f((mi & 1) ? w3hi[r] : w3lo[r]);
        part[isel] += w3v * a2v[isel] * acc[mi][ni][r];
      }
    }
  }
#pragma unroll
  for (int off = 32; off > 0; off >>= 1) {
#pragma unroll
    for (int s = 0; s < 4; ++s) part[s] += __shfl_down(part[s], off);
  }
  if (l == 0) {
#pragma unroll
    for (int s = 0; s < 4; ++s) atomicAdd(out2c + bbase + s, -part[s]);
  }
}

// ================================================================ launch
extern "C" void kernel_launch(void* const* d_in, const int* in_sizes, int n_in,
                              void* d_out, int out_size, void* d_ws, size_t ws_size,
                              hipStream_t stream) {
  const float* tin = (const float*)d_in[0];
  const float* z   = (const float*)d_in[1];
  const float* W0  = (const float*)d_in[2];
  const float* b0  = (const float*)d_in[3];
  const float* W1  = (const float*)d_in[4];
  const float* b1  = (const float*)d_in[5];
  const float* W2  = (const float*)d_in[6];
  const float* b2  = (const float*)d_in[7];
  const float* W3  = (const float*)d_in[8];
  const float* b3  = (const float*)d_in[9];
  float* out = (float*)d_out;
  float* out2 = out + 131072;  // divv region, zeroed by prep
  (void)in_sizes; (void)n_in; (void)out_size;

  char* ws = (char*)d_ws;
  size_t off = 0;
  auto take = [&](size_t bytes) {
    char* p = ws + off;
    off = (off + bytes + 255) & ~(size_t)255;
    return p;
  };
  bf* h0   = (bf*)take((size_t)4096 * 1024 * 2);   // 8 MB
  bf* h1   = (bf*)take((size_t)4096 * 1024 * 2);   // 8 MB
  bf* h2   = (bf*)take((size_t)4096 * 1024 * 2);   // 8 MB
  bf* W0T  = (bf*)take((size_t)32 * 1024 * 2);     // 64 KB
  bf* W1b  = (bf*)take((size_t)1024 * 1024 * 2);   // 2 MB
  bf* W2b  = (bf*)take((size_t)1024 * 1024 * 2);   // 2 MB
  bf* W3b  = (bf*)take((size_t)32 * 1024 * 2);     // 64 KB
  bf* W3T  = (bf*)take((size_t)1024 * 32 * 2);     // 64 KB
  const size_t avail = (ws_size > off) ? (ws_size - off) : 0;
  int NB = 4096;
  while (NB > 256 && (size_t)NB * 65536 > avail) NB >>= 1;  // only T1
  bf* T1 = (bf*)take((size_t)NB * 65536);

  prep_k<<<dim3(2465), dim3(256), 0, stream>>>(z, tin, W0, b0, W1, W2, W3,
                                               h0, W0T, W1b, W2b, W3b, W3T, out2);
  gemm_fwd<<<dim3(256), dim3(256), 0, stream>>>(h0, W1b, b1, h1);
  gemm_fwd<<<dim3(256), dim3(256), 0, stream>>>(h1, W2b, b2, h2);
  fwd3_k<<<dim3(512), dim3(256), 0, stream>>>(h2, W3b, b3, out);
  for (int cb = 0; cb < 4096; cb += NB) {
    gemm_jvp1f<<<dim3(NB), dim3(256), 0, stream>>>(
        h0 + (size_t)cb * 1024, W0T, W1b, h1 + (size_t)cb * 1024, T1);
    gemm_jvp2<<<dim3(NB), dim3(256), 0, stream>>>(
        T1, W2b, W3T, h2 + (size_t)cb * 1024, out2 + cb);
  }
}

// Round 10
// 728.970 us; speedup vs baseline: 1.0956x; 1.0342x over previous
//
#include <hip/hip_runtime.h>
#include <hip/hip_bf16.h>
#include <stdint.h>

// CNF step: 4-layer tanh MLP (33->1024->1024->1024->32) forward + exact
// Jacobian trace via 32 forward-mode tangents. B=4096, H=1024, D=32.
// f32 in/out; bf16 MFMA internally.
//
// R22 = R18 verbatim (best verified: 734.9us). R21's W3T epilogue came
// back +19us with jvp1f bit-reproduced at 160.7us/dispatch -> the W3b
// row-scatter epilogue was L1-absorbed; W3T removed. Final structure:
//   prep (fwd0 + weight conversions) -> 2x fwd GEMM (MF=4, 256 blocks)
//   -> fwd3 -> 2 chunks of {jvp1f (t0 fused into A-staging), jvp2}.
// The jvp core is DS-read-bandwidth-bound at its floor: per CU K-tile-slot
// DS = 192 ds_read_b128 ~= 2304cy vs MFMA 620cy; every LDS byte is read
// exactly once per use (24 b128/wave/K-tile minimum for the 128x64
// wave-tile, which is register-file-maximal at 2 waves/SIMD). Refuted
// alternatives: 8-phase (R13/R14), 32x32 MFMA (R15, bank conflicts),
// B-direct-from-global (R16, barrier-drained scatter), MF=4 occupancy
// (R19, +33% DS/FLOP), W3T epilogue (R21). Remaining lever would be fp8
// operands (halves DS bytes) - rejected on accuracy risk.

using bf  = __hip_bfloat16;
using bf2 = __hip_bfloat162;
typedef __attribute__((ext_vector_type(8))) short bf16x8;   // 8 bf16 = 4 VGPRs
typedef __attribute__((ext_vector_type(4))) float f32x4;    // C/D frag

__device__ __forceinline__ float b2f(bf x)    { return __bfloat162float(x); }
__device__ __forceinline__ bf    f2b(float x) { return __float2bfloat16(x); }
__device__ __forceinline__ float s2f(short s) {
  return __uint_as_float(((unsigned)(unsigned short)s) << 16);
}

__device__ __forceinline__ void gld16(const void* g, void* l) {
  __builtin_amdgcn_global_load_lds((const __attribute__((address_space(1))) void*)g,
                                   (__attribute__((address_space(3))) void*)l,
                                   16, 0, 0);
}

// ---------------------------------------------------------------- small bodies
__device__ __forceinline__ void conv_body(int blk, const float* __restrict__ src,
                                          bf* __restrict__ dst, int n4) {
  const int i = blk * 256 + threadIdx.x;
  if (i >= n4) return;
  float4 v = ((const float4*)src)[i];
  bf2* d = (bf2*)(dst + (size_t)i * 4);
  d[0] = __float22bfloat162_rn(make_float2(v.x, v.y));
  d[1] = __float22bfloat162_rn(make_float2(v.z, v.w));
}

__device__ __forceinline__ void w0t_body(int blk, const float* __restrict__ W0,
                                         bf* __restrict__ W0T) {
  const int idx = blk * 256 + threadIdx.x;
  const int i = idx >> 10, q = idx & 1023;
  W0T[idx] = f2b(W0[q * 33 + i]);
}

// ---------------------------------------------------------------- prep
// [0,128): fwd0 | [128,1152): conv W1 | [1152,2176): conv W2
// [2176,2208): conv W3 | [2208,2336): W0T | 2336: zero divv region
__global__ __launch_bounds__(256) void prep_k(const float* __restrict__ z,
                                              const float* __restrict__ tin,
                                              const float* __restrict__ W0,
                                              const float* __restrict__ b0,
                                              const float* __restrict__ W1,
                                              const float* __restrict__ W2,
                                              const float* __restrict__ W3,
                                              bf* __restrict__ h0,
                                              bf* __restrict__ W0T,
                                              bf* __restrict__ W1b,
                                              bf* __restrict__ W2b,
                                              bf* __restrict__ W3b,
                                              float* __restrict__ out2) {
  __shared__ float zs[32 * 33];
  const int f = blockIdx.x, t = threadIdx.x;
  if (f < 128) {  // fwd0: 32 samples/block
    const int s0 = f * 32;
    for (int j = t; j < 1024; j += 256) {
      const int s = j >> 5, k = j & 31;
      zs[s * 33 + k] = z[(size_t)(s0 + s) * 32 + k];
    }
    if (t < 32) zs[t * 33 + 32] = tin[0];
    __syncthreads();
#pragma unroll 1
    for (int rep = 0; rep < 4; ++rep) {
      const int hh = rep * 256 + t;
      const float* wr = W0 + (size_t)hh * 33;
      float wv[33];
#pragma unroll
      for (int k = 0; k < 33; ++k) wv[k] = wr[k];
      const float bv = b0[hh];
#pragma unroll 1
      for (int s = 0; s < 32; ++s) {
        float acc = bv;
#pragma unroll
        for (int k = 0; k < 33; ++k) acc += wv[k] * zs[s * 33 + k];
        h0[(size_t)(s0 + s) * 1024 + hh] = f2b(tanhf(acc));
      }
    }
  } else if (f < 1152) {
    conv_body(f - 128, W1, W1b, 262144);
  } else if (f < 2176) {
    conv_body(f - 1152, W2, W2b, 262144);
  } else if (f < 2208) {
    conv_body(f - 2176, W3, W3b, 8192);
  } else if (f < 2336) {
    w0t_body(f - 2208, W0, W0T);
  } else {
#pragma unroll
    for (int u = 0; u < 16; ++u) out2[u * 256 + t] = 0.f;
  }
}

// ---------------------------------------------------------------- GEMM core
// (MF*32)x128 block tile, (MF*16)x64 wave-tile (MFx4 frags), BK=64,
// glds(16B) staging with global-side XOR swizzle -> conflict-free reads,
// no ds_write instructions. MF=8: jvp2. MF=4: 128x128 tile for fwd GEMMs.
template <int MF>
__device__ __forceinline__ void gemm_core(bf* As, bf* Bs,
                                          const bf* __restrict__ A,
                                          const bf* __restrict__ B,
                                          size_t m0, size_t n0,
                                          f32x4 (&acc)[MF][4]) {
  constexpr int K = 1024;
  const int t = threadIdx.x, l = t & 63, w = t >> 6;
  const int wm = w >> 1, wn = w & 1;
  const int r15 = l & 15, q4 = l >> 4, sw = r15 & 7;

  // staging geometry: lane l covers row sub-index l>>3, seg (l&7)^(l>>3)
  const int lrow = l >> 3;
  const int lseg = (l & 7) ^ lrow;
  const bf* asrc[MF]; bf* alds[MF];
  const bf* bsrc[4]; bf* blds[4];
#pragma unroll
  for (int u = 0; u < MF; ++u) {
    const int row = w * (MF * 8) + u * 8 + lrow;     // A rows [w*MF*8, +MF*8)
    asrc[u] = A + (m0 + row) * K + lseg * 8;
    alds[u] = As + (size_t)(w * (MF * 8) + u * 8) * 64;  // wave-uniform base
  }
#pragma unroll
  for (int u = 0; u < 4; ++u) {
    const int row = w * 32 + u * 8 + lrow;           // B rows [w*32, w*32+32)
    bsrc[u] = B + (n0 + row) * K + lseg * 8;
    blds[u] = Bs + (size_t)(w * 32 + u * 8) * 64;
  }

#pragma unroll 1
  for (int k0 = 0; k0 < K; k0 += 64) {
#pragma unroll
    for (int u = 0; u < MF; ++u) gld16(asrc[u] + k0, alds[u]);
#pragma unroll
    for (int u = 0; u < 4; ++u) gld16(bsrc[u] + k0, blds[u]);
    __syncthreads();
#pragma unroll
    for (int kk = 0; kk < 2; ++kk) {
      const int sa = (kk * 4 + q4) ^ sw;
      bf16x8 af[MF], bfr[4];
#pragma unroll
      for (int i = 0; i < MF; ++i)
        af[i] = *(const bf16x8*)(As + (wm * (MF * 16) + i * 16 + r15) * 64 + sa * 8);
#pragma unroll
      for (int j = 0; j < 4; ++j)
        bfr[j] = *(const bf16x8*)(Bs + (wn * 64 + j * 16 + r15) * 64 + sa * 8);
#pragma unroll
      for (int mi = 0; mi < MF; ++mi)
#pragma unroll
        for (int ni = 0; ni < 4; ++ni)
          acc[mi][ni] = __builtin_amdgcn_mfma_f32_16x16x32_bf16(af[mi], bfr[ni], acc[mi][ni], 0, 0, 0);
    }
    __syncthreads();
  }
}

// ---------------------------------------------------------------- fwd GEMM
// MF=4: 128x128 tile, 256 blocks (32 m x 8 n) -> full GPU.
__global__ __launch_bounds__(256, 2) void gemm_fwd(const bf* __restrict__ A,
                                                   const bf* __restrict__ W,
                                                   const float* __restrict__ bias,
                                                   bf* __restrict__ H) {
  constexpr int N = 1024;
  __shared__ __align__(16) bf As[128 * 64];
  __shared__ __align__(16) bf Bs[128 * 64];
  const int t = threadIdx.x, l = t & 63, w = t >> 6;
  const int wm = w >> 1, wn = w & 1;
  const int f = blockIdx.x;                   // 256 blocks: 32 m x 8 n
  const int n_t = (f >> 3) & 7, m_t = (f & 7) + 8 * (f >> 6);
  const size_t m0 = (size_t)m_t * 128, n0 = (size_t)n_t * 128;
  const int r15 = l & 15, q4 = l >> 4;
  f32x4 acc[4][4] = {};
  gemm_core<4>(As, Bs, A, W, m0, n0, acc);
#pragma unroll
  for (int ni = 0; ni < 4; ++ni) {
    const int n = (int)n0 + wn * 64 + ni * 16 + r15;
    const float bv = bias[n];
#pragma unroll
    for (int mi = 0; mi < 4; ++mi)
#pragma unroll
      for (int r = 0; r < 4; ++r) {
        const size_t m = m0 + wm * 64 + mi * 16 + q4 * 4 + r;
        H[m * N + n] = f2b(tanhf(acc[mi][ni][r] + bv));
      }
  }
}

// ---------------------------------------------------------------- fwd3 (out)
__global__ __launch_bounds__(256) void fwd3_k(const bf* __restrict__ h2,
                                              const bf* __restrict__ W3b,
                                              const float* __restrict__ b3,
                                              float* __restrict__ out) {
  __shared__ __align__(16) bf hs[8 * 1024];
  const int t = threadIdx.x;
  const size_t bb = (size_t)blockIdx.x * 8;
  const uint4* src = (const uint4*)(h2 + bb * 1024);
  uint4* dv = (uint4*)hs;
#pragma unroll
  for (int j = 0; j < 4; ++j) dv[j * 256 + t] = src[j * 256 + t];
  __syncthreads();
  const int i = t & 31, bl = t >> 5;
  const bf2* hr = (const bf2*)(hs + bl * 1024);
  const bf2* wr = (const bf2*)(W3b + (size_t)i * 1024);
  float s = 0.f;
#pragma unroll 8
  for (int k2 = 0; k2 < 512; ++k2) {
    float2 a = __bfloat1622float2(hr[k2]);
    float2 c = __bfloat1622float2(wr[k2]);
    s += a.x * c.x + a.y * c.y;
  }
  out[(bb + bl) * 32 + i] = s + b3[i];
}

// ---------------------------------------------------------------- jvp1 (fused t0)
// A-tile computed in-kernel: T0[(b,i),k] = (1-h0[b,k]^2)*W0T[i,k].
// Thread (l,w): its LDS seg lseg=(l&7)^lrow for rows (row&7)==lrow holds
// global k-seg (l&7) -> loads are thread-invariant in k-phase. 8 swizzled
// ds_write_b128 cover each 1KB row-group exactly once (conflict-free).
__global__ __launch_bounds__(256, 2) void gemm_jvp1f(const bf* __restrict__ h0c,
                                                     const bf* __restrict__ W0T,
                                                     const bf* __restrict__ W1b,
                                                     const bf* __restrict__ h1c,
                                                     bf* __restrict__ T1) {
  constexpr int K = 1024;
  __shared__ __align__(16) bf As[256 * 64];
  __shared__ __align__(16) bf Bs[128 * 64];
  const int t = threadIdx.x, l = t & 63, w = t >> 6;
  const int wm = w >> 1, wn = w & 1;
  const int f = blockIdx.x;
  const int n_t = (f >> 3) & 7, m_t = (f & 7) + 8 * (f >> 6);
  const size_t m0 = (size_t)m_t * 256, n0 = (size_t)n_t * 128;
  const int r15 = l & 15, q4 = l >> 4, sw = r15 & 7;
  const int lrow = l >> 3, kseg = l & 7;
  const int lseg = kseg ^ lrow;

  // B staging (unchanged gld16 path)
  const bf* bsrc[4]; bf* blds[4];
#pragma unroll
  for (int u = 0; u < 4; ++u) {
    const int row = w * 32 + u * 8 + lrow;
    bsrc[u] = W1b + (n0 + row) * K + lseg * 8;
    blds[u] = Bs + (size_t)(w * 32 + u * 8) * 64;
  }

  // A compute sources: samples b0+2w, b0+2w+1; W0T rows lrow+8j
  const int b0 = (int)(m0 >> 5);
  const bf* hp0 = h0c + (size_t)(b0 + 2 * w) * K + kseg * 8;
  const bf* hp1 = hp0 + K;
  const bf* wp[4];
#pragma unroll
  for (int j = 0; j < 4; ++j) wp[j] = W0T + (size_t)(lrow + 8 * j) * K + kseg * 8;
  bf* awr[8];
#pragma unroll
  for (int u = 0; u < 8; ++u)
    awr[u] = As + (size_t)(w * 64 + u * 8 + lrow) * 64 + lseg * 8;

  f32x4 acc[8][4] = {};
  // preload k-phase 0 inputs
  bf16x8 hv0 = *(const bf16x8*)hp0;
  bf16x8 hv1 = *(const bf16x8*)hp1;
  bf16x8 wv[4];
#pragma unroll
  for (int j = 0; j < 4; ++j) wv[j] = *(const bf16x8*)wp[j];

#pragma unroll 1
  for (int k0 = 0; k0 < K; k0 += 64) {
#pragma unroll
    for (int u = 0; u < 4; ++u) gld16(bsrc[u] + k0, blds[u]);
    // compute a = 1-h^2 (f32), then write 8 swizzled b128 rows
    float a[2][8];
#pragma unroll
    for (int e = 0; e < 8; ++e) {
      const float h0v = s2f(hv0[e]);
      const float h1v = s2f(hv1[e]);
      a[0][e] = 1.f - h0v * h0v;
      a[1][e] = 1.f - h1v * h1v;
    }
#pragma unroll
    for (int u = 0; u < 8; ++u) {
      const bf16x8 wvu = wv[u & 3];
      const float* aa = a[u >> 2];
      union { bf2 b[4]; uint4 u4; } o;
#pragma unroll
      for (int p = 0; p < 4; ++p)
        o.b[p] = __float22bfloat162_rn(make_float2(aa[2 * p] * s2f(wvu[2 * p]),
                                                   aa[2 * p + 1] * s2f(wvu[2 * p + 1])));
      *(uint4*)awr[u] = o.u4;
    }
    // prefetch next k-phase inputs (wraps on last iter; data unused)
    const int kn = (k0 + 64) & (K - 1);
    hv0 = *(const bf16x8*)(hp0 + kn);
    hv1 = *(const bf16x8*)(hp1 + kn);
#pragma unroll
    for (int j = 0; j < 4; ++j) wv[j] = *(const bf16x8*)(wp[j] + kn);
    __syncthreads();
#pragma unroll
    for (int kk = 0; kk < 2; ++kk) {
      const int sa = (kk * 4 + q4) ^ sw;
      bf16x8 af[8], bfr[4];
#pragma unroll
      for (int i = 0; i < 8; ++i)
        af[i] = *(const bf16x8*)(As + (wm * 128 + i * 16 + r15) * 64 + sa * 8);
#pragma unroll
      for (int j = 0; j < 4; ++j)
        bfr[j] = *(const bf16x8*)(Bs + (wn * 64 + j * 16 + r15) * 64 + sa * 8);
#pragma unroll
      for (int mi = 0; mi < 8; ++mi)
#pragma unroll
        for (int ni = 0; ni < 4; ++ni)
          acc[mi][ni] = __builtin_amdgcn_mfma_f32_16x16x32_bf16(af[mi], bfr[ni], acc[mi][ni], 0, 0, 0);
    }
    __syncthreads();
  }

  const int bbase = (int)((m0 + wm * 128) >> 5);  // 4 samples per wave
#pragma unroll
  for (int ni = 0; ni < 4; ++ni) {
    const int n = (int)n0 + wn * 64 + ni * 16 + r15;
    float a1v[4];
#pragma unroll
    for (int s = 0; s < 4; ++s) {
      const float hv = b2f(h1c[(size_t)(bbase + s) * 1024 + n]);
      a1v[s] = 1.f - hv * hv;
    }
#pragma unroll
    for (int mi = 0; mi < 8; ++mi)
#pragma unroll
      for (int r = 0; r < 4; ++r) {
        const size_t m = m0 + wm * 128 + mi * 16 + q4 * 4 + r;
        T1[m * 1024 + n] = f2b(a1v[mi >> 1] * acc[mi][ni][r]);
      }
  }
}

// ---------------------------------------------------------------- jvp2
__global__ __launch_bounds__(256, 2) void gemm_jvp2(const bf* __restrict__ T1,
                                                    const bf* __restrict__ W2b,
                                                    const bf* __restrict__ W3b,
                                                    const bf* __restrict__ h2c,
                                                    float* __restrict__ out2c) {
  __shared__ __align__(16) bf As[256 * 64];
  __shared__ __align__(16) bf Bs[128 * 64];
  const int t = threadIdx.x, l = t & 63, w = t >> 6;
  const int wm = w >> 1, wn = w & 1;
  const int f = blockIdx.x;
  const int n_t = (f >> 3) & 7, m_t = (f & 7) + 8 * (f >> 6);
  const size_t m0 = (size_t)m_t * 256, n0 = (size_t)n_t * 128;
  const int r15 = l & 15, q4 = l >> 4;
  f32x4 acc[8][4] = {};
  gemm_core<8>(As, Bs, T1, W2b, m0, n0, acc);
  const int bbase = (int)((m0 + wm * 128) >> 5);  // 4 samples per wave
  float part[4] = {0.f, 0.f, 0.f, 0.f};
#pragma unroll
  for (int ni = 0; ni < 4; ++ni) {
    const int n = (int)n0 + wn * 64 + ni * 16 + r15;  // = p
    float a2v[4];
#pragma unroll
    for (int s = 0; s < 4; ++s) {
      const float hv = b2f(h2c[(size_t)(bbase + s) * 1024 + n]);
      a2v[s] = 1.f - hv * hv;
    }
#pragma unroll
    for (int mi = 0; mi < 8; ++mi) {
      const int isel = mi >> 1;
#pragma unroll
      for (int r = 0; r < 4; ++r) {
        const int mm = wm * 128 + mi * 16 + q4 * 4 + r;  // i = mm & 31
        part[isel] += b2f(W3b[(size_t)(mm & 31) * 1024 + n]) * a2v[isel] * acc[mi][ni][r];
      }
    }
  }
#pragma unroll
  for (int off = 32; off > 0; off >>= 1) {
#pragma unroll
    for (int s = 0; s < 4; ++s) part[s] += __shfl_down(part[s], off);
  }
  if (l == 0) {
#pragma unroll
    for (int s = 0; s < 4; ++s) atomicAdd(out2c + bbase + s, -part[s]);
  }
}

// ================================================================ launch
extern "C" void kernel_launch(void* const* d_in, const int* in_sizes, int n_in,
                              void* d_out, int out_size, void* d_ws, size_t ws_size,
                              hipStream_t stream) {
  const float* tin = (const float*)d_in[0];
  const float* z   = (const float*)d_in[1];
  const float* W0  = (const float*)d_in[2];
  const float* b0  = (const float*)d_in[3];
  const float* W1  = (const float*)d_in[4];
  const float* b1  = (const float*)d_in[5];
  const float* W2  = (const float*)d_in[6];
  const float* b2  = (const float*)d_in[7];
  const float* W3  = (const float*)d_in[8];
  const float* b3  = (const float*)d_in[9];
  float* out = (float*)d_out;
  float* out2 = out + 131072;  // divv region, zeroed by prep
  (void)in_sizes; (void)n_in; (void)out_size;

  char* ws = (char*)d_ws;
  size_t off = 0;
  auto take = [&](size_t bytes) {
    char* p = ws + off;
    off = (off + bytes + 255) & ~(size_t)255;
    return p;
  };
  bf* h0   = (bf*)take((size_t)4096 * 1024 * 2);   // 8 MB
  bf* h1   = (bf*)take((size_t)4096 * 1024 * 2);   // 8 MB
  bf* h2   = (bf*)take((size_t)4096 * 1024 * 2);   // 8 MB
  bf* W0T  = (bf*)take((size_t)32 * 1024 * 2);     // 64 KB
  bf* W1b  = (bf*)take((size_t)1024 * 1024 * 2);   // 2 MB
  bf* W2b  = (bf*)take((size_t)1024 * 1024 * 2);   // 2 MB
  bf* W3b  = (bf*)take((size_t)32 * 1024 * 2);     // 64 KB
  const size_t avail = (ws_size > off) ? (ws_size - off) : 0;
  int NB = 4096;
  while (NB > 256 && (size_t)NB * 65536 > avail) NB >>= 1;  // only T1
  bf* T1 = (bf*)take((size_t)NB * 65536);

  prep_k<<<dim3(2337), dim3(256), 0, stream>>>(z, tin, W0, b0, W1, W2, W3,
                                               h0, W0T, W1b, W2b, W3b, out2);
  gemm_fwd<<<dim3(256), dim3(256), 0, stream>>>(h0, W1b, b1, h1);
  gemm_fwd<<<dim3(256), dim3(256), 0, stream>>>(h1, W2b, b2, h2);
  fwd3_k<<<dim3(512), dim3(256), 0, stream>>>(h2, W3b, b3, out);
  for (int cb = 0; cb < 4096; cb += NB) {
    gemm_jvp1f<<<dim3(NB), dim3(256), 0, stream>>>(
        h0 + (size_t)cb * 1024, W0T, W1b, h1 + (size_t)cb * 1024, T1);
    gemm_jvp2<<<dim3(NB), dim3(256), 0, stream>>>(
        T1, W2b, W3b, h2 + (size_t)cb * 1024, out2 + cb);
  }
}